// Round 1
// baseline (166.540 us; speedup 1.0000x reference)
//
#include <hip/hip_runtime.h>

// ---------------- types / helpers ----------------
typedef unsigned short u16;
typedef float f32x4 __attribute__((ext_vector_type(4)));
typedef short bf16x8 __attribute__((ext_vector_type(8)));
typedef u16 u16x4 __attribute__((ext_vector_type(4)));

__device__ __forceinline__ u16 f2bf(float f) {
    unsigned u = __float_as_uint(f);
    u = (u + 0x7FFFu + ((u >> 16) & 1u)) >> 16;
    return (u16)u;
}

#define LOG2E 1.4426950408889634f

#if __has_builtin(__builtin_amdgcn_exp2f)
__device__ __forceinline__ float exp2_fast(float x) { return __builtin_amdgcn_exp2f(x); }
#else
__device__ __forceinline__ float exp2_fast(float x) { return __expf(x * 0.6931471805599453f); }
#endif

__device__ __forceinline__ unsigned pack2bf(float a, float b) {
    unsigned ua = __float_as_uint(a) + 0x8000u;
    unsigned ub = __float_as_uint(b) + 0x8000u;
#if __has_builtin(__builtin_amdgcn_perm)
    return __builtin_amdgcn_perm(ub, ua, 0x07060302u);
#else
    return ((ua >> 16) & 0xFFFFu) | (ub & 0xFFFF0000u);
#endif
}

#if __has_builtin(__builtin_amdgcn_cvt_pk_bf16_f32)
typedef __bf16 bf2_t __attribute__((ext_vector_type(2)));
__device__ __forceinline__ unsigned cvtpk(float a, float b) {
    bf2_t r = __builtin_amdgcn_cvt_pk_bf16_f32(a, b);
    return __builtin_bit_cast(unsigned, r);
}
#else
__device__ __forceinline__ unsigned cvtpk(float a, float b) { return pack2bf(a, b); }
#endif

__device__ __forceinline__ bf16x8 bc8(uint4 u) { return __builtin_bit_cast(bf16x8, u); }

// async 16B/lane global->LDS DMA; lds dst = wave-uniform base + lane*16.
#if __has_builtin(__builtin_amdgcn_global_load_lds)
typedef const __attribute__((address_space(1))) void* as1cv;
typedef __attribute__((address_space(3))) void* as3v;
__device__ __forceinline__ void dma16(const void* g, void* lds_base, int lane) {
    __builtin_amdgcn_global_load_lds((as1cv)g, (as3v)lds_base, 16, 0, 0);
}
#else
__device__ __forceinline__ void dma16(const void* g, void* lds_base, int lane) {
    *(uint4*)((char*)lds_base + lane * 16) = *(const uint4*)g;
}
#endif

// Problem constants
#define BB 2
#define HH 56
#define SQ 3136
#define HP 62
#define SK 3844
#define VT_STRIDE 3856

// workspace offsets (u16 units); total 5,744,640 u16 = 11.49 MB
#define WS_Q    0         // 6272*256
#define WS_K    1605632   // 7688*256
#define WS_VT   3573760   // 512*3856
#define WS_WT   5548032   // 3*256*256 bf16 transposed weights WT[m][d][k]

// ---------------- kernel 0: weight transpose+convert (+V tail zero) ----------------
// grid (4,4,3): 64x64 tiles. wt[m][d][k] = W_m[k][d] * (m==0 ? LOG2E : 1), bf16.
__global__ __launch_bounds__(256) void wprep_kernel(const float* __restrict__ Wq,
                                                    const float* __restrict__ Wk,
                                                    const float* __restrict__ Wv,
                                                    u16* __restrict__ wt,
                                                    u16* __restrict__ vtb) {
    __shared__ u16 T[64][72];
    int m = blockIdx.z;
    const float* W = (m == 0) ? Wq : ((m == 1) ? Wk : Wv);
    float sc = (m == 0) ? LOG2E : 1.0f;
    int kx = blockIdx.x * 64, dx = blockIdx.y * 64;
    int tid = threadIdx.x;
    int r16 = tid >> 4, c4 = (tid & 15) * 4;
#pragma unroll
    for (int p = 0; p < 4; ++p) {
        int kr = p * 16 + r16;
        float4 f = *(const float4*)&W[(size_t)(kx + kr) * 256 + dx + c4];
        T[c4 + 0][kr] = f2bf(f.x * sc);
        T[c4 + 1][kr] = f2bf(f.y * sc);
        T[c4 + 2][kr] = f2bf(f.z * sc);
        T[c4 + 3][kr] = f2bf(f.w * sc);
    }
    __syncthreads();
#pragma unroll
    for (int p = 0; p < 4; ++p) {
        int dr = p * 16 + r16;
        u16x4 v = {T[dr][c4], T[dr][c4 + 1], T[dr][c4 + 2], T[dr][c4 + 3]};
        *(u16x4*)&wt[(size_t)m * 65536 + (size_t)(dx + dr) * 256 + kx + c4] = v;
    }
    // zero V^T tail columns [3844..3855] so staged-but-masked PV reads are 0, not garbage
    if (m == 0 && blockIdx.x == 0 && blockIdx.y == 0) {
        for (int i = tid; i < 512 * 12; i += 256) {
            int row = i / 12, col = 3844 + (i - row * 12);
            vtb[(size_t)row * VT_STRIDE + col] = 0;
        }
    }
}

// ---------------- kernel 1: projections (LDS-free, B from pre-transposed bf16 WT) ----
// grid (121, 3 modes, 2 n-halves). mode: 0=Q (M=6272), 1=K, 2=V-transposed (M=7688).
__global__ __launch_bounds__(256, 4) void proj_kernel(const float* __restrict__ x,
                                                      const u16* __restrict__ wt,
                                                      const float* __restrict__ bq,
                                                      const float* __restrict__ bk,
                                                      const float* __restrict__ bv,
                                                      u16* __restrict__ qout,
                                                      u16* __restrict__ kout,
                                                      u16* __restrict__ vtout) {
    int mode = blockIdx.y, nz = blockIdx.z;
    int mbase = blockIdx.x * 64;
    int M = (mode == 0) ? (BB * SQ) : (BB * SK);
    if (mbase >= M) return;
    int tid = threadIdx.x;
    int wave = tid >> 6, quad = (tid >> 4) & 3, l16 = tid & 15;
    const float* bias = (mode == 0) ? bq : ((mode == 1) ? bk : bv);
    const u16* Wm = wt + (size_t)mode * 65536 + (size_t)(nz * 128) * 256;
    // per-lane B row base: row = nz*128 + nt*16 + l16, cols k = s*32 + quad*8 .. +7
    const u16* wr = Wm + (size_t)l16 * 256 + quad * 8;

    int m_a = mbase + wave * 16 + l16;
    if (m_a >= M) m_a = M - 1;
    int xrow;
    if (mode == 0) {
        xrow = m_a;
    } else {
        int bb = (m_a >= SK) ? 1 : 0;
        int sp = m_a - bb * SK;
        int hp = sp / HP, wp = sp - hp * HP;
        int hs = hp - 3; hs = hs < 0 ? -hs : (hs >= HH ? 110 - hs : hs);
        int ws_ = wp - 3; ws_ = ws_ < 0 ? -ws_ : (ws_ >= HH ? 110 - ws_ : ws_);
        xrow = bb * SQ + hs * HH + ws_;
    }
    const float* xr = x + (size_t)xrow * 256;

    f32x4 acc[8];
#pragma unroll
    for (int i = 0; i < 8; i++) acc[i] = (f32x4){0.f, 0.f, 0.f, 0.f};

#pragma unroll
    for (int s = 0; s < 8; ++s) {
        float4 f0 = *(const float4*)&xr[s * 32 + quad * 8];
        float4 f1 = *(const float4*)&xr[s * 32 + quad * 8 + 4];
        uint4 aw = (uint4){pack2bf(f0.x, f0.y), pack2bf(f0.z, f0.w),
                           pack2bf(f1.x, f1.y), pack2bf(f1.z, f1.w)};
        bf16x8 af = bc8(aw);
#pragma unroll
        for (int nt = 0; nt < 8; nt++) {
            bf16x8 bfrag = *(const bf16x8*)&wr[nt * 4096 + s * 32];
            acc[nt] = __builtin_amdgcn_mfma_f32_16x16x32_bf16(af, bfrag, acc[nt], 0, 0, 0);
        }
    }

    int mrow_base = mbase + wave * 16 + quad * 4;
    if (mode == 2) {
#pragma unroll
        for (int nt = 0; nt < 8; nt++) {
            int c = nz * 128 + nt * 16 + l16;
            float bvv = bias[c];
#pragma unroll
            for (int p = 0; p < 4; p += 2) {
                int m = mrow_base + p;
                if (m + 1 < M) {
                    int bb = (m >= SK) ? 1 : 0;
                    int kp = m - bb * SK;
                    unsigned pk = pack2bf(acc[nt][p] + bvv, acc[nt][p + 1] + bvv);
                    *(unsigned*)&vtout[(size_t)(bb * 256 + c) * VT_STRIDE + kp] = pk;
                }
            }
        }
    } else {
#pragma unroll
        for (int r = 0; r < 4; r++) {
            int m = mrow_base + r;
            if (m >= M) continue;
#pragma unroll
            for (int nt = 0; nt < 8; nt++) {
                int c = nz * 128 + nt * 16 + l16;
                float v = acc[nt][r] + bias[c] * ((mode == 0) ? LOG2E : 1.0f);
                u16 hv = f2bf(v);
                if (mode == 0) qout[((size_t)m << 8) + c] = hv;
                else           kout[((size_t)m << 8) + c] = hv;
            }
        }
    }
}

// ---------------- kernel 2: flash attention (full key range, fused finalize) --------
// grid (16 bh, 49 qsub): blockIdx.x = bh so all q-blocks of a head share one XCD's L2.
// 4 waves; each wave owns ALL 64 queries and tiles {th, th+4} per 128-key round.
// 31 rounds cover all 3844 keys; PV uses K=32 16x16x32 MFMA with the k-axis
// permutation pi(quad,j) = (j<4 ? tileA : tileB, key quad*4+(j&3)) so the P
// A-fragment is {cvtpk pairs} in natural order (no cross-lane moves) and V
// B-fragments are two b64 LDS reads per 16-d half. l = sum(p) via f32 VALU adds.
// Epilogue: in-block merge then wave 0 writes out = gamma*O/l + x directly.
__global__ __launch_bounds__(256, 4) void attn_kernel(const u16* __restrict__ qb,
                                                      const u16* __restrict__ kb,
                                                      const u16* __restrict__ vtb,
                                                      const float* __restrict__ x,
                                                      const float* __restrict__ gammap,
                                                      float* __restrict__ out) {
    __shared__ __align__(16) u16 S[16384];   // buf b at b*8192: K +0, V +4096

    int tid = threadIdx.x;
    int th = tid >> 6, lane = tid & 63, quad = lane >> 4, l16 = lane & 15;
    int bh = blockIdx.x;
    int b = bh >> 3, h = bh & 7;
    int qsub = blockIdx.y * 64;

    // 4 Q B-fragments (16x16x32): n=l16 -> query qsub+i*16+l16, k=quad*8+j
    bf16x8 qf[4];
#pragma unroll
    for (int i = 0; i < 4; ++i)
        qf[i] = *(const bf16x8*)&qb[((size_t)(b * SQ + qsub + i * 16 + l16) << 8) + h * 32 + quad * 8];

    const u16* kg = kb + ((size_t)(b * SK) << 8) + h * 32;
    const u16* vg = vtb + (size_t)(b * 256 + h * 32) * VT_STRIDE;

    f32x4 o[4][2];
    f32x4 lacc = (f32x4){0.f, 0.f, 0.f, 0.f};
#pragma unroll
    for (int i = 0; i < 4; ++i) {
        o[i][0] = (f32x4){0.f, 0.f, 0.f, 0.f};
        o[i][1] = (f32x4){0.f, 0.f, 0.f, 0.f};
    }

    // staging: wave th issues K groups {th, th+4} and V groups {th, th+4}.
    auto stage = [&](int r_ch, int buf) {
        u16* base = &S[buf * 8192];
        int kbase = r_ch * 128;
#pragma unroll
        for (int i = 0; i < 2; ++i) {
            int g = th + i * 4;
            int grow = kbase + g * 16 + (lane & 15);
            if (grow > SK - 1) grow = SK - 1;
            dma16(kg + ((size_t)grow << 8) + (lane >> 4) * 8, base + g * 512, lane);
            int col = kbase + (2 * g + (lane >> 5)) * 8;
            if (col > VT_STRIDE - 8) col = VT_STRIDE - 8;
            dma16(vg + (size_t)(lane & 31) * VT_STRIDE + col, base + 4096 + g * 512, lane);
        }
    };

    stage(0, 0);
    __syncthreads();              // drains chunk-0 DMA
    stage(1, 1);                  // in flight during round 0

    int tA = th, tB = th + 4;
    int vOffA = tA * 512 + (((quad >> 1) * 32 + l16) << 3) + (quad & 1) * 4;
    int vOffB = tB * 512 + (((quad >> 1) * 32 + l16) << 3) + (quad & 1) * 4;

    for (int r = 0; r < 31; ++r) {
        const u16* Kl = &S[(r & 1) * 8192];
        const u16* Vl = Kl + 4096;
        bf16x8 kfA = *(const bf16x8*)&Kl[tA * 512 + lane * 8];
        bf16x8 kfB = *(const bf16x8*)&Kl[tB * 512 + lane * 8];
        uint2 wA0 = *(const uint2*)&Vl[vOffA];         // Vt[l16][tA keys quad*4..+3]
        uint2 wB0 = *(const uint2*)&Vl[vOffB];
        uint2 wA1 = *(const uint2*)&Vl[vOffA + 128];   // d = 16+l16
        uint2 wB1 = *(const uint2*)&Vl[vOffB + 128];
        bf16x8 V0 = bc8((uint4){wA0.x, wA0.y, wB0.x, wB0.y});
        bf16x8 V1 = bc8((uint4){wA1.x, wA1.y, wB1.x, wB1.y});

        f32x4 eA[4], eB[4];
#pragma unroll
        for (int i = 0; i < 4; ++i)
            eA[i] = __builtin_amdgcn_mfma_f32_16x16x32_bf16(kfA, qf[i], (f32x4){0.f, 0.f, 0.f, 0.f}, 0, 0, 0);
#pragma unroll
        for (int i = 0; i < 4; ++i)
            eB[i] = __builtin_amdgcn_mfma_f32_16x16x32_bf16(kfB, qf[i], (f32x4){0.f, 0.f, 0.f, 0.f}, 0, 0, 0);

        bool tail = (r == 30);
#pragma unroll
        for (int i = 0; i < 4; ++i) {
            float pA0 = exp2_fast(eA[i][0]), pA1 = exp2_fast(eA[i][1]);
            float pA2 = exp2_fast(eA[i][2]), pA3 = exp2_fast(eA[i][3]);
            float pB0 = exp2_fast(eB[i][0]), pB1 = exp2_fast(eB[i][1]);
            float pB2 = exp2_fast(eB[i][2]), pB3 = exp2_fast(eB[i][3]);
            if (tail) {
                int kA0 = 3840 + tA * 16 + quad * 4;
                pA0 = (kA0 + 0 < SK) ? pA0 : 0.f;
                pA1 = (kA0 + 1 < SK) ? pA1 : 0.f;
                pA2 = (kA0 + 2 < SK) ? pA2 : 0.f;
                pA3 = (kA0 + 3 < SK) ? pA3 : 0.f;
                pB0 = 0.f; pB1 = 0.f; pB2 = 0.f; pB3 = 0.f;
            }
            lacc[i] += ((pA0 + pA1) + (pA2 + pA3)) + ((pB0 + pB1) + (pB2 + pB3));
            bf16x8 pa = bc8((uint4){cvtpk(pA0, pA1), cvtpk(pA2, pA3),
                                    cvtpk(pB0, pB1), cvtpk(pB2, pB3)});
            o[i][0] = __builtin_amdgcn_mfma_f32_16x16x32_bf16(pa, V0, o[i][0], 0, 0, 0);
            o[i][1] = __builtin_amdgcn_mfma_f32_16x16x32_bf16(pa, V1, o[i][1], 0, 0, 0);
        }
        __syncthreads();                       // drains DMA(r+1); frees buf r&1
        if (r + 2 < 31) stage(r + 2, r & 1);
    }

    // ---- two-stage merge of 4 t-quarters via LDS (DMA quiet after final barrier) ----
    float* mg = (float*)&S[0];                 // stage1: 20.5KB, stage2: 10.25KB
    {
        int slot = ((th & 1) * 64 + lane) * 40;
        if (th >= 2) {
#pragma unroll
            for (int i = 0; i < 4; ++i) {
                *(f32x4*)&mg[slot + i * 8]     = o[i][0];
                *(f32x4*)&mg[slot + i * 8 + 4] = o[i][1];
            }
            *(f32x4*)&mg[slot + 32] = lacc;
        }
        __syncthreads();
        if (th < 2) {
#pragma unroll
            for (int i = 0; i < 4; ++i) {
                o[i][0] += *(const f32x4*)&mg[slot + i * 8];
                o[i][1] += *(const f32x4*)&mg[slot + i * 8 + 4];
            }
            lacc += *(const f32x4*)&mg[slot + 32];
        }
        __syncthreads();
    }
    {
        int slot = lane * 40;
        if (th == 1) {
#pragma unroll
            for (int i = 0; i < 4; ++i) {
                *(f32x4*)&mg[slot + i * 8]     = o[i][0];
                *(f32x4*)&mg[slot + i * 8 + 4] = o[i][1];
            }
            *(f32x4*)&mg[slot + 32] = lacc;
        }
        __syncthreads();
        if (th == 0) {
#pragma unroll
            for (int i = 0; i < 4; ++i) {
                o[i][0] += *(const f32x4*)&mg[slot + i * 8];
                o[i][1] += *(const f32x4*)&mg[slot + i * 8 + 4];
            }
            lacc += *(const f32x4*)&mg[slot + 32];
            // cross-quad reduce: l[query l16] complete in every lane
#pragma unroll
            for (int c = 0; c < 4; ++c) {
                float v = lacc[c];
                v += __shfl_xor(v, 16);
                v += __shfl_xor(v, 32);
                lacc[c] = v;
            }
            float g = gammap[0];
#pragma unroll
            for (int i = 0; i < 4; ++i) {
#pragma unroll
                for (int r2 = 0; r2 < 4; ++r2) {
                    float l = __shfl(lacc[i], quad * 4 + r2);   // lane with l16==qrow
                    float scl = g / l;
                    int q = qsub + i * 16 + quad * 4 + r2;
                    size_t base = ((size_t)(b * SQ + q) << 8) + h * 32 + l16;
                    out[base]      = o[i][0][r2] * scl + x[base];
                    out[base + 16] = o[i][1][r2] * scl + x[base + 16];
                }
            }
        }
    }
}

// ---------------- launcher ----------------
extern "C" void kernel_launch(void* const* d_in, const int* in_sizes, int n_in,
                              void* d_out, int out_size, void* d_ws, size_t ws_size,
                              hipStream_t stream) {
    const float* x     = (const float*)d_in[0];
    const float* Wq    = (const float*)d_in[1];
    const float* bq    = (const float*)d_in[2];
    const float* Wk    = (const float*)d_in[3];
    const float* bk    = (const float*)d_in[4];
    const float* Wv    = (const float*)d_in[5];
    const float* bv    = (const float*)d_in[6];
    const float* gamma = (const float*)d_in[7];
    float* out = (float*)d_out;

    u16* ws   = (u16*)d_ws;
    u16* qbuf = ws + WS_Q;
    u16* kbuf = ws + WS_K;
    u16* vtb  = ws + WS_VT;
    u16* wt   = ws + WS_WT;

    wprep_kernel<<<dim3(4, 4, 3), 256, 0, stream>>>(Wq, Wk, Wv, wt, vtb);
    proj_kernel<<<dim3(121, 3, 2), 256, 0, stream>>>(x, wt, bq, bk, bv, qbuf, kbuf, vtb);
    attn_kernel<<<dim3(16, 49), 256, 0, stream>>>(qbuf, kbuf, vtb, x, gamma, out);
}

// Round 2
// 154.534 us; speedup vs baseline: 1.0777x; 1.0777x over previous
//
#include <hip/hip_runtime.h>

// ---------------- types / helpers ----------------
typedef unsigned short u16;
typedef float f32x4 __attribute__((ext_vector_type(4)));
typedef short bf16x8 __attribute__((ext_vector_type(8)));
typedef u16 u16x4 __attribute__((ext_vector_type(4)));

__device__ __forceinline__ u16 f2bf(float f) {
    unsigned u = __float_as_uint(f);
    u = (u + 0x7FFFu + ((u >> 16) & 1u)) >> 16;
    return (u16)u;
}

#define LOG2E 1.4426950408889634f

#if __has_builtin(__builtin_amdgcn_exp2f)
__device__ __forceinline__ float exp2_fast(float x) { return __builtin_amdgcn_exp2f(x); }
#else
__device__ __forceinline__ float exp2_fast(float x) { return __expf(x * 0.6931471805599453f); }
#endif

__device__ __forceinline__ unsigned pack2bf(float a, float b) {
    unsigned ua = __float_as_uint(a) + 0x8000u;
    unsigned ub = __float_as_uint(b) + 0x8000u;
#if __has_builtin(__builtin_amdgcn_perm)
    return __builtin_amdgcn_perm(ub, ua, 0x07060302u);
#else
    return ((ua >> 16) & 0xFFFFu) | (ub & 0xFFFF0000u);
#endif
}

#if __has_builtin(__builtin_amdgcn_cvt_pk_bf16_f32)
typedef __bf16 bf2_t __attribute__((ext_vector_type(2)));
__device__ __forceinline__ unsigned cvtpk(float a, float b) {
    bf2_t r = __builtin_amdgcn_cvt_pk_bf16_f32(a, b);
    return __builtin_bit_cast(unsigned, r);
}
#else
__device__ __forceinline__ unsigned cvtpk(float a, float b) { return pack2bf(a, b); }
#endif

__device__ __forceinline__ bf16x8 bc8(uint4 u) { return __builtin_bit_cast(bf16x8, u); }

// async 16B/lane global->LDS DMA; lds dst = wave-uniform base + lane*16.
#if __has_builtin(__builtin_amdgcn_global_load_lds)
typedef const __attribute__((address_space(1))) void* as1cv;
typedef __attribute__((address_space(3))) void* as3v;
__device__ __forceinline__ void dma16(const void* g, void* lds_base, int lane) {
    __builtin_amdgcn_global_load_lds((as1cv)g, (as3v)lds_base, 16, 0, 0);
}
#else
__device__ __forceinline__ void dma16(const void* g, void* lds_base, int lane) {
    *(uint4*)((char*)lds_base + lane * 16) = *(const uint4*)g;
}
#endif

// Problem constants
#define BB 2
#define HH 56
#define SQ 3136
#define HP 62
#define SK 3844
#define VT_STRIDE 3856

// workspace offsets (u16 units)
#define WS_Q    0         // 6272*256
#define WS_K    1605632   // 7688*256
#define WS_VT   3573760   // 512*3856
#define WS_WT   5548032   // 3*65536 bf16 fragment-packed weights

// ---------------- kernel 0: weight fragment-pack (+V tail zero) ----------------
// wtf[mode][f = ((nz*8+s)*8+nt)][lane=(quad*16+l16)][j=0..7]
//   = W_mode[k = s*32+quad*8+j][d = nz*128+nt*16+l16] * (mode==0 ? LOG2E : 1)
// so proj's B-frag load for (s,nt) is ONE coalesced 16B/lane read at uniform+lane*16.
// grid (16, 3): block handles 8 frags; 32 threads/frag; thread does lanes {sub, sub+32}.
__global__ __launch_bounds__(256) void wprep_kernel(const float* __restrict__ Wq,
                                                    const float* __restrict__ Wk,
                                                    const float* __restrict__ Wv,
                                                    u16* __restrict__ wtf,
                                                    u16* __restrict__ vtb) {
    int mode = blockIdx.y;
    const float* W = (mode == 0) ? Wq : ((mode == 1) ? Wk : Wv);
    float sc = (mode == 0) ? LOG2E : 1.0f;
    int tid = threadIdx.x;
    int f = blockIdx.x * 8 + (tid >> 5);
    int sub = tid & 31;
    int nz = f >> 6, s = (f >> 3) & 7, nt = f & 7;
#pragma unroll
    for (int e = 0; e < 2; ++e) {
        int L = sub + e * 32;
        int quad = L >> 4, l16 = L & 15;
        int d = nz * 128 + nt * 16 + l16;
        int k0 = s * 32 + quad * 8;
        u16 tmp[8];
#pragma unroll
        for (int j = 0; j < 8; ++j)
            tmp[j] = f2bf(W[(size_t)(k0 + j) * 256 + d] * sc);
        *(uint4*)&wtf[(size_t)mode * 65536 + (size_t)f * 512 + (size_t)L * 8] = *(uint4*)tmp;
    }
    // zero V^T tail columns [3844..3855] so staged-but-masked PV reads are 0, not garbage
    if (mode == 0 && blockIdx.x == 0) {
        for (int i = tid; i < 512 * 12; i += 256) {
            int row = i / 12, col = 3844 + (i - row * 12);
            vtb[(size_t)row * VT_STRIDE + col] = 0;
        }
    }
}

// ---------------- kernel 1: projections (LDS-free; B coalesced from wtf) -----------
// grid (121, 3 modes, 2 n-halves). mode: 0=Q (M=6272), 1=K, 2=V-transposed (M=7688).
__global__ __launch_bounds__(256, 4) void proj_kernel(const float* __restrict__ x,
                                                      const u16* __restrict__ wtf,
                                                      const float* __restrict__ bq,
                                                      const float* __restrict__ bk,
                                                      const float* __restrict__ bv,
                                                      u16* __restrict__ qout,
                                                      u16* __restrict__ kout,
                                                      u16* __restrict__ vtout) {
    int mode = blockIdx.y, nz = blockIdx.z;
    int mbase = blockIdx.x * 64;
    int M = (mode == 0) ? (BB * SQ) : (BB * SK);
    if (mbase >= M) return;
    int tid = threadIdx.x;
    int wave = tid >> 6, quad = (tid >> 4) & 3, l16 = tid & 15;
    const float* bias = (mode == 0) ? bq : ((mode == 1) ? bk : bv);
    // coalesced fragment base: + (s*8+nt)*512 per step
    const u16* wf = wtf + (size_t)mode * 65536 + (size_t)nz * 32768 + (size_t)(quad * 16 + l16) * 8;

    int m_a = mbase + wave * 16 + l16;
    if (m_a >= M) m_a = M - 1;
    int xrow;
    if (mode == 0) {
        xrow = m_a;
    } else {
        int bb = (m_a >= SK) ? 1 : 0;
        int sp = m_a - bb * SK;
        int hp = sp / HP, wp = sp - hp * HP;
        int hs = hp - 3; hs = hs < 0 ? -hs : (hs >= HH ? 110 - hs : hs);
        int ws_ = wp - 3; ws_ = ws_ < 0 ? -ws_ : (ws_ >= HH ? 110 - ws_ : ws_);
        xrow = bb * SQ + hs * HH + ws_;
    }
    const float* xr = x + (size_t)xrow * 256;

    f32x4 acc[8];
#pragma unroll
    for (int i = 0; i < 8; i++) acc[i] = (f32x4){0.f, 0.f, 0.f, 0.f};

#pragma unroll
    for (int s = 0; s < 8; ++s) {
        float4 f0 = *(const float4*)&xr[s * 32 + quad * 8];
        float4 f1 = *(const float4*)&xr[s * 32 + quad * 8 + 4];
        uint4 aw = (uint4){pack2bf(f0.x, f0.y), pack2bf(f0.z, f0.w),
                           pack2bf(f1.x, f1.y), pack2bf(f1.z, f1.w)};
        bf16x8 af = bc8(aw);
#pragma unroll
        for (int nt = 0; nt < 8; nt++) {
            bf16x8 bfrag = *(const bf16x8*)&wf[(s * 8 + nt) * 512];
            acc[nt] = __builtin_amdgcn_mfma_f32_16x16x32_bf16(af, bfrag, acc[nt], 0, 0, 0);
        }
    }

    int mrow_base = mbase + wave * 16 + quad * 4;
    if (mode == 2) {
#pragma unroll
        for (int nt = 0; nt < 8; nt++) {
            int c = nz * 128 + nt * 16 + l16;
            float bvv = bias[c];
#pragma unroll
            for (int p = 0; p < 4; p += 2) {
                int m = mrow_base + p;
                if (m + 1 < M) {
                    int bb = (m >= SK) ? 1 : 0;
                    int kp = m - bb * SK;
                    unsigned pk = pack2bf(acc[nt][p] + bvv, acc[nt][p + 1] + bvv);
                    *(unsigned*)&vtout[(size_t)(bb * 256 + c) * VT_STRIDE + kp] = pk;
                }
            }
        }
    } else {
#pragma unroll
        for (int r = 0; r < 4; r++) {
            int m = mrow_base + r;
            if (m >= M) continue;
#pragma unroll
            for (int nt = 0; nt < 8; nt++) {
                int c = nz * 128 + nt * 16 + l16;
                float v = acc[nt][r] + bias[c] * ((mode == 0) ? LOG2E : 1.0f);
                u16 hv = f2bf(v);
                if (mode == 0) qout[((size_t)m << 8) + c] = hv;
                else           kout[((size_t)m << 8) + c] = hv;
            }
        }
    }
}

// ---------------- kernel 2: flash attention (barrier-free decoupled waves) ---------
// grid (16 bh, 49 qsub). 4 waves; each wave owns ALL 64 queries and key tiles
// {th, th+4} of each 128-key round, AND stages exactly those tiles itself — so
// no wave ever reads another wave's LDS region. The main loop therefore has NO
// __syncthreads: 3 LDS buffers (16KB each), DMA issued 2 rounds ahead, per-wave
// counted s_waitcnt vmcnt(4) (T4). Each CU runs up to 12 fully-decoupled wave
// streams. Single barrier before the epilogue merge.
__global__ __launch_bounds__(256, 3) void attn_kernel(const u16* __restrict__ qb,
                                                      const u16* __restrict__ kb,
                                                      const u16* __restrict__ vtb,
                                                      const float* __restrict__ x,
                                                      const float* __restrict__ gammap,
                                                      float* __restrict__ out) {
    __shared__ __align__(16) u16 S[24576];   // buf b at b*8192 u16: K +0, V +4096

    int tid = threadIdx.x;
    int th = tid >> 6, lane = tid & 63, quad = lane >> 4, l16 = lane & 15;
    int bh = blockIdx.x;
    int b = bh >> 3, h = bh & 7;
    int qsub = blockIdx.y * 64;

    // 4 Q B-fragments (16x16x32): n=l16 -> query qsub+i*16+l16, k=quad*8+j
    bf16x8 qf[4];
#pragma unroll
    for (int i = 0; i < 4; ++i)
        qf[i] = *(const bf16x8*)&qb[((size_t)(b * SQ + qsub + i * 16 + l16) << 8) + h * 32 + quad * 8];

    const u16* kg = kb + ((size_t)(b * SK) << 8) + h * 32;
    const u16* vg = vtb + (size_t)(b * 256 + h * 32) * VT_STRIDE;

    f32x4 o[4][2];
    f32x4 lacc = (f32x4){0.f, 0.f, 0.f, 0.f};
#pragma unroll
    for (int i = 0; i < 4; ++i) {
        o[i][0] = (f32x4){0.f, 0.f, 0.f, 0.f};
        o[i][1] = (f32x4){0.f, 0.f, 0.f, 0.f};
    }

    // staging: wave th issues K groups {th, th+4} and V groups {th, th+4} (4 DMAs).
    auto stage = [&](int r_ch, int buf) {
        u16* base = &S[buf * 8192];
        int kbase = r_ch * 128;
#pragma unroll
        for (int i = 0; i < 2; ++i) {
            int g = th + i * 4;
            int grow = kbase + g * 16 + (lane & 15);
            if (grow > SK - 1) grow = SK - 1;
            dma16(kg + ((size_t)grow << 8) + (lane >> 4) * 8, base + g * 512, lane);
            int col = kbase + (2 * g + (lane >> 5)) * 8;
            if (col > VT_STRIDE - 8) col = VT_STRIDE - 8;
            dma16(vg + (size_t)(lane & 31) * VT_STRIDE + col, base + 4096 + g * 512, lane);
        }
    };

    int tA = th, tB = th + 4;
    int vOffA = tA * 512 + (((quad >> 1) * 32 + l16) << 3) + (quad & 1) * 4;
    int vOffB = tB * 512 + (((quad >> 1) * 32 + l16) << 3) + (quad & 1) * 4;

    auto round_body = [&](int bR, bool tail) {
        const u16* Kl = &S[bR * 8192];
        const u16* Vl = Kl + 4096;
        bf16x8 kfA = *(const bf16x8*)&Kl[tA * 512 + lane * 8];
        bf16x8 kfB = *(const bf16x8*)&Kl[tB * 512 + lane * 8];
        uint2 wA0 = *(const uint2*)&Vl[vOffA];         // Vt[l16][tA keys quad*4..+3]
        uint2 wB0 = *(const uint2*)&Vl[vOffB];
        uint2 wA1 = *(const uint2*)&Vl[vOffA + 128];   // d = 16+l16
        uint2 wB1 = *(const uint2*)&Vl[vOffB + 128];
        bf16x8 V0 = bc8((uint4){wA0.x, wA0.y, wB0.x, wB0.y});
        bf16x8 V1 = bc8((uint4){wA1.x, wA1.y, wB1.x, wB1.y});

        f32x4 eA[4], eB[4];
#pragma unroll
        for (int i = 0; i < 4; ++i)
            eA[i] = __builtin_amdgcn_mfma_f32_16x16x32_bf16(kfA, qf[i], (f32x4){0.f, 0.f, 0.f, 0.f}, 0, 0, 0);
#pragma unroll
        for (int i = 0; i < 4; ++i)
            eB[i] = __builtin_amdgcn_mfma_f32_16x16x32_bf16(kfB, qf[i], (f32x4){0.f, 0.f, 0.f, 0.f}, 0, 0, 0);

#pragma unroll
        for (int i = 0; i < 4; ++i) {
            float pA0 = exp2_fast(eA[i][0]), pA1 = exp2_fast(eA[i][1]);
            float pA2 = exp2_fast(eA[i][2]), pA3 = exp2_fast(eA[i][3]);
            float pB0 = exp2_fast(eB[i][0]), pB1 = exp2_fast(eB[i][1]);
            float pB2 = exp2_fast(eB[i][2]), pB3 = exp2_fast(eB[i][3]);
            if (tail) {
                int kA0 = 3840 + tA * 16 + quad * 4;
                pA0 = (kA0 + 0 < SK) ? pA0 : 0.f;
                pA1 = (kA0 + 1 < SK) ? pA1 : 0.f;
                pA2 = (kA0 + 2 < SK) ? pA2 : 0.f;
                pA3 = (kA0 + 3 < SK) ? pA3 : 0.f;
                pB0 = 0.f; pB1 = 0.f; pB2 = 0.f; pB3 = 0.f;
            }
            lacc[i] += ((pA0 + pA1) + (pA2 + pA3)) + ((pB0 + pB1) + (pB2 + pB3));
            bf16x8 pa = bc8((uint4){cvtpk(pA0, pA1), cvtpk(pA2, pA3),
                                    cvtpk(pB0, pB1), cvtpk(pB2, pB3)});
            o[i][0] = __builtin_amdgcn_mfma_f32_16x16x32_bf16(pa, V0, o[i][0], 0, 0, 0);
            o[i][1] = __builtin_amdgcn_mfma_f32_16x16x32_bf16(pa, V1, o[i][1], 0, 0, 0);
        }
    };

    stage(0, 0);
    stage(1, 1);
    int bR = 0, bS = 2;
    for (int r = 0; r < 30; ++r) {
        // completes round r's 4 DMAs; round r+1's stay in flight
        asm volatile("s_waitcnt vmcnt(4)" ::: "memory");
        if (r + 2 < 31) stage(r + 2, bS);
        round_body(bR, false);
        bR = (bR == 2) ? 0 : bR + 1;
        bS = (bS == 2) ? 0 : bS + 1;
    }
    asm volatile("s_waitcnt vmcnt(0)" ::: "memory");
    round_body(0, true);                       // round 30, buf 30%3=0

    __syncthreads();                           // all waves done; LDS reusable

    // ---- two-stage merge of 4 t-quarters via LDS ----
    float* mg = (float*)&S[0];
    {
        int slot = ((th & 1) * 64 + lane) * 40;
        if (th >= 2) {
#pragma unroll
            for (int i = 0; i < 4; ++i) {
                *(f32x4*)&mg[slot + i * 8]     = o[i][0];
                *(f32x4*)&mg[slot + i * 8 + 4] = o[i][1];
            }
            *(f32x4*)&mg[slot + 32] = lacc;
        }
        __syncthreads();
        if (th < 2) {
#pragma unroll
            for (int i = 0; i < 4; ++i) {
                o[i][0] += *(const f32x4*)&mg[slot + i * 8];
                o[i][1] += *(const f32x4*)&mg[slot + i * 8 + 4];
            }
            lacc += *(const f32x4*)&mg[slot + 32];
        }
        __syncthreads();
    }
    {
        int slot = lane * 40;
        if (th == 1) {
#pragma unroll
            for (int i = 0; i < 4; ++i) {
                *(f32x4*)&mg[slot + i * 8]     = o[i][0];
                *(f32x4*)&mg[slot + i * 8 + 4] = o[i][1];
            }
            *(f32x4*)&mg[slot + 32] = lacc;
        }
        __syncthreads();
        if (th == 0) {
#pragma unroll
            for (int i = 0; i < 4; ++i) {
                o[i][0] += *(const f32x4*)&mg[slot + i * 8];
                o[i][1] += *(const f32x4*)&mg[slot + i * 8 + 4];
            }
            lacc += *(const f32x4*)&mg[slot + 32];
            // cross-quad reduce: l[query l16] complete in every lane
#pragma unroll
            for (int c = 0; c < 4; ++c) {
                float v = lacc[c];
                v += __shfl_xor(v, 16);
                v += __shfl_xor(v, 32);
                lacc[c] = v;
            }
            float g = gammap[0];
#pragma unroll
            for (int i = 0; i < 4; ++i) {
#pragma unroll
                for (int r2 = 0; r2 < 4; ++r2) {
                    float l = __shfl(lacc[i], quad * 4 + r2);   // lane with l16==qrow
                    float scl = g / l;
                    int q = qsub + i * 16 + quad * 4 + r2;
                    size_t base = ((size_t)(b * SQ + q) << 8) + h * 32 + l16;
                    out[base]      = o[i][0][r2] * scl + x[base];
                    out[base + 16] = o[i][1][r2] * scl + x[base + 16];
                }
            }
        }
    }
}

// ---------------- launcher ----------------
extern "C" void kernel_launch(void* const* d_in, const int* in_sizes, int n_in,
                              void* d_out, int out_size, void* d_ws, size_t ws_size,
                              hipStream_t stream) {
    const float* x     = (const float*)d_in[0];
    const float* Wq    = (const float*)d_in[1];
    const float* bq    = (const float*)d_in[2];
    const float* Wk    = (const float*)d_in[3];
    const float* bk    = (const float*)d_in[4];
    const float* Wv    = (const float*)d_in[5];
    const float* bv    = (const float*)d_in[6];
    const float* gamma = (const float*)d_in[7];
    float* out = (float*)d_out;

    u16* ws   = (u16*)d_ws;
    u16* qbuf = ws + WS_Q;
    u16* kbuf = ws + WS_K;
    u16* vtb  = ws + WS_VT;
    u16* wtf  = ws + WS_WT;

    wprep_kernel<<<dim3(16, 3), 256, 0, stream>>>(Wq, Wk, Wv, wtf, vtb);
    proj_kernel<<<dim3(121, 3, 2), 256, 0, stream>>>(x, wtf, bq, bk, bv, qbuf, kbuf, vtb);
    attn_kernel<<<dim3(16, 49), 256, 0, stream>>>(qbuf, kbuf, vtb, x, gamma, out);
}